// Round 1
// baseline (349.201 us; speedup 1.0000x reference)
//
#include <hip/hip_runtime.h>
#include <hip/hip_bf16.h>
#include <math.h>

#define NN 50000
#define DD 128
#define ALPHA 0.1f
#define BETA 0.5f
#define ROWS_PER_BLOCK 64
#define THREADS 256

// ---------------------------------------------------------------------------
// Kernel 1: build CSR row pointer from sorted edge_row.
// rp[r] = first edge index e with edge_row[e] >= r; rp[N] = E.
// Each thread e in [0, E] writes the boundary rows it owns.
// ---------------------------------------------------------------------------
__global__ void build_rowptr(const int* __restrict__ edge_row, int E,
                             int* __restrict__ rp) {
    int e = blockIdx.x * blockDim.x + threadIdx.x;
    if (e > E) return;
    if (e == 0) {
        int r0 = edge_row[0];
        for (int r = 0; r <= r0; ++r) rp[r] = 0;
    } else if (e == E) {
        int rl = edge_row[E - 1];
        for (int r = rl + 1; r <= NN; ++r) rp[r] = E;
    } else {
        int rprev = edge_row[e - 1];
        int rcur  = edge_row[e];
        for (int r = rprev + 1; r <= rcur; ++r) rp[r] = e;
    }
}

// ---------------------------------------------------------------------------
// Kernel 2: fused aggregate + linear + blend for a 64-row tile.
//   support = 0.9 * (A@h) + 0.1 * h0          (per-wave row aggregation)
//   out     = theta*(support@W.T + b) + (1-theta)*support
// LDS: support tile fp32 [64][129] (33KB) + W bf16 [128][130] (33.3KB)
//      -> ~66KB -> 2 blocks/CU.
// ---------------------------------------------------------------------------
__global__ __launch_bounds__(THREADS) void fused_gconv(
    const float* __restrict__ h, const float* __restrict__ h0,
    const int* __restrict__ edge_col, const float* __restrict__ edge_vals,
    const float* __restrict__ W, const float* __restrict__ b,
    const int* __restrict__ lptr, const int* __restrict__ rp,
    float* __restrict__ out)
{
    __shared__ float sS[ROWS_PER_BLOCK][DD + 1];      // support tile (pad 129)
    __shared__ __hip_bfloat16 sW[DD][DD + 2];          // W as bf16 (pad 130)

    const int tid = threadIdx.x;
    const int r0  = blockIdx.x * ROWS_PER_BLOCK;

    const int lv = *lptr;
    const float theta = logf(BETA / (float)lv + 1.0f);

    // --- stage W (bf16) into LDS ---
    for (int i = tid; i < DD * DD; i += THREADS) {
        int o = i >> 7, k = i & 127;
        sW[o][k] = __float2bfloat16(W[i]);
    }

    // --- aggregation: wave w owns rows ri = w, w+4, ... ; lane owns float2 ---
    const int wave = tid >> 6;
    const int lane = tid & 63;
    for (int ri = wave; ri < ROWS_PER_BLOCK; ri += 4) {
        const int r = r0 + ri;
        float2 acc = {0.f, 0.f};
        if (r < NN) {
            const int e0 = rp[r], e1 = rp[r + 1];
            for (int e = e0; e < e1; ++e) {
                const int   c = edge_col[e];
                const float v = edge_vals[e];
                const float2 hv =
                    *reinterpret_cast<const float2*>(h + (size_t)c * DD + 2 * lane);
                acc.x = fmaf(v, hv.x, acc.x);
                acc.y = fmaf(v, hv.y, acc.y);
            }
            const float2 h0v =
                *reinterpret_cast<const float2*>(h0 + (size_t)r * DD + 2 * lane);
            acc.x = (1.0f - ALPHA) * acc.x + ALPHA * h0v.x;
            acc.y = (1.0f - ALPHA) * acc.y + ALPHA * h0v.y;
        }
        sS[ri][2 * lane]     = acc.x;
        sS[ri][2 * lane + 1] = acc.y;
    }
    __syncthreads();

    // --- GEMM: thread (tr, tc) computes rows tr*4..+3, cols tc*8..+7 ---
    const int tr = tid >> 4;   // 0..15
    const int tc = tid & 15;   // 0..15
    float acc[4][8];
    #pragma unroll
    for (int i = 0; i < 4; ++i)
        #pragma unroll
        for (int j = 0; j < 8; ++j) acc[i][j] = 0.f;

    for (int k = 0; k < DD; ++k) {
        float a[4], w[8];
        #pragma unroll
        for (int i = 0; i < 4; ++i) a[i] = sS[tr * 4 + i][k];
        #pragma unroll
        for (int j = 0; j < 8; ++j) w[j] = __bfloat162float(sW[tc * 8 + j][k]);
        #pragma unroll
        for (int i = 0; i < 4; ++i)
            #pragma unroll
            for (int j = 0; j < 8; ++j) acc[i][j] = fmaf(a[i], w[j], acc[i][j]);
    }

    // --- epilogue: out = theta*(lin + b) + (1-theta)*support ---
    #pragma unroll
    for (int j = 0; j < 8; ++j) {
        const int cc = tc * 8 + j;
        const float bb = b[cc];
        #pragma unroll
        for (int i = 0; i < 4; ++i) {
            const int rr = r0 + tr * 4 + i;
            if (rr < NN) {
                const float sup = sS[tr * 4 + i][cc];
                out[(size_t)rr * DD + cc] =
                    theta * (acc[i][j] + bb) + (1.0f - theta) * sup;
            }
        }
    }
}

extern "C" void kernel_launch(void* const* d_in, const int* in_sizes, int n_in,
                              void* d_out, int out_size, void* d_ws, size_t ws_size,
                              hipStream_t stream) {
    const float* h         = (const float*)d_in[0];
    const float* h0        = (const float*)d_in[1];
    const int*   edge_row  = (const int*)d_in[2];
    const int*   edge_col  = (const int*)d_in[3];
    const float* edge_vals = (const float*)d_in[4];
    const float* W         = (const float*)d_in[5];
    const float* b         = (const float*)d_in[6];
    const int*   lptr      = (const int*)d_in[7];
    const int E = in_sizes[2];

    int* rp = (int*)d_ws;  // N+1 ints (~200KB)

    build_rowptr<<<(E + 1 + 255) / 256, 256, 0, stream>>>(edge_row, E, rp);

    const int nblocks = (NN + ROWS_PER_BLOCK - 1) / ROWS_PER_BLOCK;
    fused_gconv<<<nblocks, THREADS, 0, stream>>>(
        h, h0, edge_col, edge_vals, W, b, lptr, rp, (float*)d_out);
}

// Round 2
// 134.459 us; speedup vs baseline: 2.5971x; 2.5971x over previous
//
#include <hip/hip_runtime.h>
#include <hip/hip_bf16.h>
#include <math.h>

#define NN 50000
#define DD 128
#define ALPHA 0.1f
#define BETA 0.5f
#define RPB 64           // rows per block
#define THREADS 512      // 8 waves
#define SPAD 132         // support tile pad (fp32, keeps rows 16B-aligned)
#define WPAD 136         // W^T pad (bf16, keeps rows 16B-aligned: 272B = 17*16)

// ---------------------------------------------------------------------------
// Kernel 1: build CSR row pointer from sorted edge_row.
// ---------------------------------------------------------------------------
__global__ void build_rowptr(const int* __restrict__ edge_row, int E,
                             int* __restrict__ rp) {
    int e = blockIdx.x * blockDim.x + threadIdx.x;
    if (e > E) return;
    if (e == 0) {
        int r0 = edge_row[0];
        for (int r = 0; r <= r0; ++r) rp[r] = 0;
    } else if (e == E) {
        int rl = edge_row[E - 1];
        for (int r = rl + 1; r <= NN; ++r) rp[r] = E;
    } else {
        int rprev = edge_row[e - 1];
        int rcur  = edge_row[e];
        for (int r = rprev + 1; r <= rcur; ++r) rp[r] = e;
    }
}

__device__ __forceinline__ float bf16lo(unsigned u) {
    return __uint_as_float(u << 16);
}
__device__ __forceinline__ float bf16hi(unsigned u) {
    return __uint_as_float(u & 0xffff0000u);
}

// ---------------------------------------------------------------------------
// Kernel 2: fused aggregate + linear + blend, 64-row tile, 512 threads.
//   aggregation: per wave, 2 edges spatially (32 lanes x float4 each),
//                unrolled x4 -> 8 edges / 4 gathers in flight.
//   GEMM: W^T in LDS as bf16, ds_read_b128 weight loads, 2x8 per thread.
// ---------------------------------------------------------------------------
__global__ __launch_bounds__(THREADS, 4) void fused_gconv(
    const float* __restrict__ h, const float* __restrict__ h0,
    const int* __restrict__ edge_col, const float* __restrict__ edge_vals,
    const float* __restrict__ W, const float* __restrict__ b,
    const int* __restrict__ lptr, const int* __restrict__ rp,
    float* __restrict__ out)
{
    __shared__ float sS[RPB][SPAD];            // support tile fp32 (33.8 KB)
    __shared__ __hip_bfloat16 sWt[DD][WPAD];   // W transposed bf16 (34.8 KB)

    const int tid = threadIdx.x;
    const int r0  = blockIdx.x * RPB;

    const int lv = *lptr;
    const float theta  = logf(BETA / (float)lv + 1.0f);
    const float mtheta = 1.0f - theta;

    // --- stage W transposed into LDS (coalesced float4 global reads) ---
    for (int i = tid * 4; i < DD * DD; i += THREADS * 4) {
        const float4 w4 = *reinterpret_cast<const float4*>(W + i);
        const int o = i >> 7;        // output col (row of W)
        const int k = i & 127;       // input feature
        sWt[k + 0][o] = __float2bfloat16(w4.x);
        sWt[k + 1][o] = __float2bfloat16(w4.y);
        sWt[k + 2][o] = __float2bfloat16(w4.z);
        sWt[k + 3][o] = __float2bfloat16(w4.w);
    }

    // --- aggregation ---
    const int wave = tid >> 6;     // 0..7
    const int lane = tid & 63;
    const int p    = lane >> 5;    // which edge of the pair this half handles
    const int li   = lane & 31;    // feature quad: features li*4 .. li*4+3

    for (int ri = wave; ri < RPB; ri += 8) {
        const int r = r0 + ri;
        float4 A[4];
        #pragma unroll
        for (int u = 0; u < 4; ++u) A[u] = make_float4(0.f, 0.f, 0.f, 0.f);

        float4 sup = make_float4(0.f, 0.f, 0.f, 0.f);
        if (r < NN) {
            const int e0 = rp[r], e1 = rp[r + 1];
            for (int eb = e0; eb < e1; eb += 8) {
                #pragma unroll
                for (int u = 0; u < 4; ++u) {
                    const int e  = eb + 2 * u + p;
                    const int ee = min(e, e1 - 1);          // clamp (safe load)
                    const int   c = edge_col[ee];
                    const float v = (e < e1) ? edge_vals[ee] : 0.0f;
                    const float4 hv = *reinterpret_cast<const float4*>(
                        h + (size_t)c * DD + li * 4);
                    A[u].x = fmaf(v, hv.x, A[u].x);
                    A[u].y = fmaf(v, hv.y, A[u].y);
                    A[u].z = fmaf(v, hv.z, A[u].z);
                    A[u].w = fmaf(v, hv.w, A[u].w);
                }
            }
            float4 s;
            s.x = (A[0].x + A[1].x) + (A[2].x + A[3].x);
            s.y = (A[0].y + A[1].y) + (A[2].y + A[3].y);
            s.z = (A[0].z + A[1].z) + (A[2].z + A[3].z);
            s.w = (A[0].w + A[1].w) + (A[2].w + A[3].w);
            // combine the two edge-halves (lane <-> lane^32)
            s.x += __shfl_xor(s.x, 32);
            s.y += __shfl_xor(s.y, 32);
            s.z += __shfl_xor(s.z, 32);
            s.w += __shfl_xor(s.w, 32);
            const float4 h0v = *reinterpret_cast<const float4*>(
                h0 + (size_t)r * DD + li * 4);
            sup.x = fmaf(1.0f - ALPHA, s.x, ALPHA * h0v.x);
            sup.y = fmaf(1.0f - ALPHA, s.y, ALPHA * h0v.y);
            sup.z = fmaf(1.0f - ALPHA, s.z, ALPHA * h0v.z);
            sup.w = fmaf(1.0f - ALPHA, s.w, ALPHA * h0v.w);
        }
        if (p == 0) {
            *reinterpret_cast<float4*>(&sS[ri][li * 4]) = sup;
        }
    }
    __syncthreads();

    // --- GEMM: thread (tr, tc) computes rows tr*2..+1, cols tc*8..+7 ---
    const int tr = tid >> 4;   // 0..31
    const int tc = tid & 15;   // 0..15
    float acc[2][8];
    #pragma unroll
    for (int i = 0; i < 2; ++i)
        #pragma unroll
        for (int j = 0; j < 8; ++j) acc[i][j] = 0.f;

    for (int k = 0; k < DD; k += 4) {
        const float4 a0 = *reinterpret_cast<const float4*>(&sS[tr * 2 + 0][k]);
        const float4 a1 = *reinterpret_cast<const float4*>(&sS[tr * 2 + 1][k]);
        const float aa0[4] = {a0.x, a0.y, a0.z, a0.w};
        const float aa1[4] = {a1.x, a1.y, a1.z, a1.w};
        #pragma unroll
        for (int kk = 0; kk < 4; ++kk) {
            const uint4 wr = *reinterpret_cast<const uint4*>(&sWt[k + kk][tc * 8]);
            float w[8];
            w[0] = bf16lo(wr.x); w[1] = bf16hi(wr.x);
            w[2] = bf16lo(wr.y); w[3] = bf16hi(wr.y);
            w[4] = bf16lo(wr.z); w[5] = bf16hi(wr.z);
            w[6] = bf16lo(wr.w); w[7] = bf16hi(wr.w);
            #pragma unroll
            for (int j = 0; j < 8; ++j) {
                acc[0][j] = fmaf(aa0[kk], w[j], acc[0][j]);
                acc[1][j] = fmaf(aa1[kk], w[j], acc[1][j]);
            }
        }
    }

    // --- epilogue: out = theta*(lin + b) + (1-theta)*support (float4) ---
    #pragma unroll
    for (int i = 0; i < 2; ++i) {
        const int ri = tr * 2 + i;
        const int rr = r0 + ri;
        if (rr >= NN) continue;
        #pragma unroll
        for (int jj = 0; jj < 8; jj += 4) {
            const int cc = tc * 8 + jj;
            const float4 bv  = *reinterpret_cast<const float4*>(&b[cc]);
            const float4 sup = *reinterpret_cast<const float4*>(&sS[ri][cc]);
            float4 o4;
            o4.x = theta * (acc[i][jj + 0] + bv.x) + mtheta * sup.x;
            o4.y = theta * (acc[i][jj + 1] + bv.y) + mtheta * sup.y;
            o4.z = theta * (acc[i][jj + 2] + bv.z) + mtheta * sup.z;
            o4.w = theta * (acc[i][jj + 3] + bv.w) + mtheta * sup.w;
            *reinterpret_cast<float4*>(out + (size_t)rr * DD + cc) = o4;
        }
    }
}

extern "C" void kernel_launch(void* const* d_in, const int* in_sizes, int n_in,
                              void* d_out, int out_size, void* d_ws, size_t ws_size,
                              hipStream_t stream) {
    const float* h         = (const float*)d_in[0];
    const float* h0        = (const float*)d_in[1];
    const int*   edge_row  = (const int*)d_in[2];
    const int*   edge_col  = (const int*)d_in[3];
    const float* edge_vals = (const float*)d_in[4];
    const float* W         = (const float*)d_in[5];
    const float* b         = (const float*)d_in[6];
    const int*   lptr      = (const int*)d_in[7];
    const int E = in_sizes[2];

    int* rp = (int*)d_ws;  // N+1 ints (~200KB)

    build_rowptr<<<(E + 1 + 255) / 256, 256, 0, stream>>>(edge_row, E, rp);

    const int nblocks = (NN + RPB - 1) / RPB;
    fused_gconv<<<nblocks, THREADS, 0, stream>>>(
        h, h0, edge_col, edge_vals, W, b, lptr, rp, (float*)d_out);
}